// Round 1
// baseline (325.461 us; speedup 1.0000x reference)
//
#include <hip/hip_runtime.h>

#define B_ 2
#define N_ 2048
#define D_ 1024
#define H_ 16
#define DH_ 64

typedef _Float16 half8 __attribute__((ext_vector_type(8)));
typedef _Float16 half4 __attribute__((ext_vector_type(4)));
typedef float f32x4 __attribute__((ext_vector_type(4)));

// ---------------------------------------------------------------------------
// Convert fp32 inputs (queries/keys/values) to fp16, same layout (B,N,D).
// grid (2048, 3), block 256; 8 elems/thread.
__global__ __launch_bounds__(256) void convert_x_kernel(
    const float* __restrict__ q, const float* __restrict__ k,
    const float* __restrict__ v, _Float16* __restrict__ dst) {
  const float* s = (blockIdx.y == 0) ? q : (blockIdx.y == 1) ? k : v;
  _Float16* d = dst + (size_t)blockIdx.y * ((size_t)B_ * N_ * D_);
  size_t idx = ((size_t)blockIdx.x * 256 + threadIdx.x) * 8;
  float4 a = *(const float4*)(s + idx);
  float4 b = *(const float4*)(s + idx + 4);
  half8 h;
  h[0] = (_Float16)a.x; h[1] = (_Float16)a.y; h[2] = (_Float16)a.z; h[3] = (_Float16)a.w;
  h[4] = (_Float16)b.x; h[5] = (_Float16)b.y; h[6] = (_Float16)b.z; h[7] = (_Float16)b.w;
  *(half8*)(d + idx) = h;
}

// ---------------------------------------------------------------------------
// Convert+transpose the four (D,D) fp32 weights to fp16 W^T (N-major, K-contig).
// grid (16, 16, 4), block 256. 64x64 tiles via LDS.
__global__ __launch_bounds__(256) void convert_w_kernel(
    const float* __restrict__ Wq, const float* __restrict__ Wk,
    const float* __restrict__ Wv, const float* __restrict__ Wo,
    _Float16* __restrict__ WtAll) {
  const float* W = (blockIdx.z == 0) ? Wq : (blockIdx.z == 1) ? Wk
                  : (blockIdx.z == 2) ? Wv : Wo;
  _Float16* Wt = WtAll + (size_t)blockIdx.z * D_ * D_;
  __shared__ float tile[64][65];
  int k0 = blockIdx.y * 64, n0 = blockIdx.x * 64;
  int tr = threadIdx.x >> 4, tc = threadIdx.x & 15;
#pragma unroll
  for (int i = 0; i < 4; ++i) {
    int r = tr + i * 16;  // k local
    float4 va = *(const float4*)(W + (size_t)(k0 + r) * D_ + n0 + tc * 4);
    tile[r][tc * 4 + 0] = va.x; tile[r][tc * 4 + 1] = va.y;
    tile[r][tc * 4 + 2] = va.z; tile[r][tc * 4 + 3] = va.w;
  }
  __syncthreads();
#pragma unroll
  for (int i = 0; i < 4; ++i) {
    int r = tr + i * 16;  // n local
    half4 hv;
    hv[0] = (_Float16)tile[tc * 4 + 0][r];
    hv[1] = (_Float16)tile[tc * 4 + 1][r];
    hv[2] = (_Float16)tile[tc * 4 + 2][r];
    hv[3] = (_Float16)tile[tc * 4 + 3][r];
    *(half4*)(Wt + (size_t)(n0 + r) * D_ + k0 + tc * 4) = hv;
  }
}

// ---------------------------------------------------------------------------
// fp16 MFMA GEMM: C[M=4096, N=1024] = A[M,K=1024] * Bt[N,K]^T
// mode 0: write fp16 to head-split layout (B,H,N,DH)
// mode 1: write fp32 row-major (d_out)
#define BM 128
#define BN 128
#define BK 32
#define LDA 40  // padded LDS row stride (halves); 80B rows, 16B-aligned

__global__ __launch_bounds__(256) void gemm_f16_kernel(
    const _Float16* __restrict__ A, const _Float16* __restrict__ Bt,
    _Float16* __restrict__ Chead, float* __restrict__ Cf32, int mode) {
  __shared__ __attribute__((aligned(16))) _Float16 As[BM][LDA];
  __shared__ __attribute__((aligned(16))) _Float16 Bs[BN][LDA];
  const int K = D_;
  int tid = threadIdx.x;
  int m0 = blockIdx.y * BM, n0 = blockIdx.x * BN;
  int lane = tid & 63, w = tid >> 6;
  int quad = lane >> 4, l15 = lane & 15;
  int wm = (w >> 1) * 64, wn = (w & 1) * 64;
  f32x4 acc[4][4] = {};
  int sr = tid >> 2;         // 0..63
  int sc = (tid & 3) * 8;    // 0,8,16,24

  for (int kt = 0; kt < K; kt += BK) {
#pragma unroll
    for (int p = 0; p < 2; ++p) {
      int r = sr + p * 64;
      *(half8*)&As[r][sc] = *(const half8*)(A + (size_t)(m0 + r) * K + kt + sc);
      *(half8*)&Bs[r][sc] = *(const half8*)(Bt + (size_t)(n0 + r) * K + kt + sc);
    }
    __syncthreads();
    half8 af[4], bf[4];
#pragma unroll
    for (int mt = 0; mt < 4; ++mt)
      af[mt] = *(const half8*)&As[wm + mt * 16 + l15][quad * 8];
#pragma unroll
    for (int nt = 0; nt < 4; ++nt)
      bf[nt] = *(const half8*)&Bs[wn + nt * 16 + l15][quad * 8];
#pragma unroll
    for (int mt = 0; mt < 4; ++mt)
#pragma unroll
      for (int nt = 0; nt < 4; ++nt)
        acc[mt][nt] = __builtin_amdgcn_mfma_f32_16x16x32_f16(
            af[mt], bf[nt], acc[mt][nt], 0, 0, 0);
    __syncthreads();
  }

#pragma unroll
  for (int mt = 0; mt < 4; ++mt) {
    int mrow = m0 + wm + mt * 16 + quad * 4;
#pragma unroll
    for (int nt = 0; nt < 4; ++nt) {
      int jcol = n0 + wn + nt * 16 + l15;
#pragma unroll
      for (int r = 0; r < 4; ++r) {
        float val = acc[mt][nt][r];
        int m = mrow + r;
        if (mode == 0) {
          int b = m >> 11, n = m & (N_ - 1);
          int h = jcol >> 6, dh = jcol & (DH_ - 1);
          Chead[((((size_t)(b * H_ + h)) * N_ + n) * DH_) + dh] = (_Float16)val;
        } else {
          Cf32[(size_t)m * D_ + jcol] = val;
        }
      }
    }
  }
}

// ---------------------------------------------------------------------------
// Flash attention. grid (N/64, B*H), block 256 (4 waves).
// Q/K/V in (B,H,N,DH) fp16. Output Hd in (B,N,D) fp16 (heads merged).
#define LQS 72  // padded LDS stride (halves); 144B rows, 16B-aligned

__global__ __launch_bounds__(256) void attn_kernel(
    const _Float16* __restrict__ Qh, const _Float16* __restrict__ Kh,
    const _Float16* __restrict__ Vh, const int* __restrict__ vlen,
    _Float16* __restrict__ Hd) {
  __shared__ __attribute__((aligned(16))) _Float16 Qs[64][LQS];
  __shared__ __attribute__((aligned(16))) _Float16 Ks[64][LQS];
  __shared__ __attribute__((aligned(16))) _Float16 Vt[64][LQS];  // [dh][key]
  __shared__ __attribute__((aligned(16))) _Float16 Ps[64][LQS];  // [q][key]
  int bh = blockIdx.y;
  int q0 = blockIdx.x * 64;
  int b = bh >> 4, h = bh & (H_ - 1);
  int vl = vlen[bh];
  int tid = threadIdx.x, lane = tid & 63, w = tid >> 6;
  int quad = lane >> 4, l15 = lane & 15;
  const _Float16* Qb = Qh + (size_t)bh * N_ * DH_;
  const _Float16* Kb = Kh + (size_t)bh * N_ * DH_;
  const _Float16* Vb = Vh + (size_t)bh * N_ * DH_;

  // stage Q tile (64 rows x 64) once
#pragma unroll
  for (int p = 0; p < 2; ++p) {
    int g = p * 256 + tid;
    int qr = g >> 3, dg = (g & 7) * 8;
    *(half8*)&Qs[qr][dg] = *(const half8*)(Qb + (size_t)(q0 + qr) * DH_ + dg);
  }

  float mrow[4] = {-1e30f, -1e30f, -1e30f, -1e30f};
  float lrow[4] = {0.f, 0.f, 0.f, 0.f};
  f32x4 Oacc[4] = {};
  const float scale = 0.125f;  // 1/sqrt(64)

  int KT = (vl + 63) >> 6;
  for (int kt = 0; kt < KT; ++kt) {
    int k0 = kt * 64;
    __syncthreads();  // (A) prev PV reads done before restaging K/V
    // stage K tile
#pragma unroll
    for (int p = 0; p < 2; ++p) {
      int g = p * 256 + tid;
      int kr = g >> 3, dg = (g & 7) * 8;
      *(half8*)&Ks[kr][dg] = *(const half8*)(Kb + (size_t)(k0 + kr) * DH_ + dg);
    }
    // stage V tile transposed: Vt[dh][key]
#pragma unroll
    for (int p = 0; p < 2; ++p) {
      int dhg = w + p * 4;      // 0..7
      int keyl = lane;          // 0..63
      half8 vv = *(const half8*)(Vb + (size_t)(k0 + keyl) * DH_ + dhg * 8);
#pragma unroll
      for (int u = 0; u < 8; ++u) Vt[dhg * 8 + u][keyl] = vv[u];
    }
    __syncthreads();  // (B)

    // S = Q * K^T for this wave's 16 q-rows x 64 keys
    half8 qa0 = *(const half8*)&Qs[w * 16 + l15][quad * 8];
    half8 qa1 = *(const half8*)&Qs[w * 16 + l15][32 + quad * 8];
    f32x4 s[4];
#pragma unroll
    for (int nt = 0; nt < 4; ++nt) {
      half8 kb0 = *(const half8*)&Ks[nt * 16 + l15][quad * 8];
      half8 kb1 = *(const half8*)&Ks[nt * 16 + l15][32 + quad * 8];
      f32x4 c = {};
      c = __builtin_amdgcn_mfma_f32_16x16x32_f16(qa0, kb0, c, 0, 0, 0);
      c = __builtin_amdgcn_mfma_f32_16x16x32_f16(qa1, kb1, c, 0, 0, 0);
      s[nt] = c;
    }
    // scale + mask (mask depends only on key = col)
#pragma unroll
    for (int nt = 0; nt < 4; ++nt) {
      int key = k0 + nt * 16 + l15;
      bool valid = key < vl;
#pragma unroll
      for (int r = 0; r < 4; ++r) {
        float t = s[nt][r] * scale;
        s[nt][r] = valid ? t : -1e30f;
      }
    }
    // online softmax: row = quad*4 + r, cols spread over l15 (16 lanes) x 4 nt
    float alpha[4];
#pragma unroll
    for (int r = 0; r < 4; ++r) {
      float v = fmaxf(fmaxf(s[0][r], s[1][r]), fmaxf(s[2][r], s[3][r]));
      v = fmaxf(v, __shfl_xor(v, 1));
      v = fmaxf(v, __shfl_xor(v, 2));
      v = fmaxf(v, __shfl_xor(v, 4));
      v = fmaxf(v, __shfl_xor(v, 8));
      float mi = fmaxf(mrow[r], v);
      alpha[r] = __expf(mrow[r] - mi);
      mrow[r] = mi;
    }
    float rsum[4] = {0.f, 0.f, 0.f, 0.f};
#pragma unroll
    for (int nt = 0; nt < 4; ++nt)
#pragma unroll
      for (int r = 0; r < 4; ++r) {
        float p = __expf(s[nt][r] - mrow[r]);
        s[nt][r] = p;
        rsum[r] += p;
      }
#pragma unroll
    for (int r = 0; r < 4; ++r) {
      float v = rsum[r];
      v += __shfl_xor(v, 1);
      v += __shfl_xor(v, 2);
      v += __shfl_xor(v, 4);
      v += __shfl_xor(v, 8);
      lrow[r] = alpha[r] * lrow[r] + v;
    }
#pragma unroll
    for (int dt = 0; dt < 4; ++dt)
#pragma unroll
      for (int r = 0; r < 4; ++r) Oacc[dt][r] *= alpha[r];

    // P: C-layout -> LDS -> A-layout
#pragma unroll
    for (int nt = 0; nt < 4; ++nt)
#pragma unroll
      for (int r = 0; r < 4; ++r)
        Ps[w * 16 + quad * 4 + r][nt * 16 + l15] = (_Float16)s[nt][r];
    __syncthreads();  // (C)

    // O += P * V
    half8 pa0 = *(const half8*)&Ps[w * 16 + l15][quad * 8];
    half8 pa1 = *(const half8*)&Ps[w * 16 + l15][32 + quad * 8];
#pragma unroll
    for (int dt = 0; dt < 4; ++dt) {
      half8 vb0 = *(const half8*)&Vt[dt * 16 + l15][quad * 8];
      half8 vb1 = *(const half8*)&Vt[dt * 16 + l15][32 + quad * 8];
      Oacc[dt] = __builtin_amdgcn_mfma_f32_16x16x32_f16(pa0, vb0, Oacc[dt], 0, 0, 0);
      Oacc[dt] = __builtin_amdgcn_mfma_f32_16x16x32_f16(pa1, vb1, Oacc[dt], 0, 0, 0);
    }
  }

  // epilogue: divide by l, write merged-head layout (B,N,D) fp16
  float inv_l[4];
#pragma unroll
  for (int r = 0; r < 4; ++r) inv_l[r] = 1.0f / lrow[r];
#pragma unroll
  for (int dt = 0; dt < 4; ++dt)
#pragma unroll
    for (int r = 0; r < 4; ++r) {
      float val = Oacc[dt][r] * inv_l[r];
      int qrow = q0 + w * 16 + quad * 4 + r;
      Hd[((size_t)(b * N_ + qrow)) * D_ + h * DH_ + dt * 16 + l15] = (_Float16)val;
    }
}

// ---------------------------------------------------------------------------
extern "C" void kernel_launch(void* const* d_in, const int* in_sizes, int n_in,
                              void* d_out, int out_size, void* d_ws, size_t ws_size,
                              hipStream_t stream) {
  const float* q  = (const float*)d_in[0];
  const float* k  = (const float*)d_in[1];
  const float* v  = (const float*)d_in[2];
  const int*   vl = (const int*)d_in[3];
  const float* Wq = (const float*)d_in[4];
  const float* Wk = (const float*)d_in[5];
  const float* Wv = (const float*)d_in[6];
  const float* Wo = (const float*)d_in[7];

  const size_t XSZ = (size_t)B_ * N_ * D_;  // 4M elements
  const size_t WSZ = (size_t)D_ * D_;       // 1M elements
  _Float16* ws = (_Float16*)d_ws;
  _Float16* Xf = ws;                 // 3*XSZ halves (fp16 q,k,v inputs)
  _Float16* Wt = Xf + 3 * XSZ;       // 4*WSZ halves (fp16 W^T x4)
  _Float16* Qh = Wt + 4 * WSZ;       // XSZ
  _Float16* Kh = Qh + XSZ;           // XSZ
  _Float16* Vh = Kh + XSZ;           // XSZ
  _Float16* Hd = Vh + XSZ;           // XSZ

  convert_x_kernel<<<dim3(2048, 3), 256, 0, stream>>>(q, k, v, Xf);
  convert_w_kernel<<<dim3(16, 16, 4), 256, 0, stream>>>(Wq, Wk, Wv, Wo, Wt);

  dim3 gg(D_ / BN, (B_ * N_) / BM);  // (8, 32)
  gemm_f16_kernel<<<gg, 256, 0, stream>>>(Xf,           Wt,           Qh, nullptr, 0);
  gemm_f16_kernel<<<gg, 256, 0, stream>>>(Xf + XSZ,     Wt + WSZ,     Kh, nullptr, 0);
  gemm_f16_kernel<<<gg, 256, 0, stream>>>(Xf + 2 * XSZ, Wt + 2 * WSZ, Vh, nullptr, 0);

  attn_kernel<<<dim3(N_ / 64, B_ * H_), 256, 0, stream>>>(Qh, Kh, Vh, vl, Hd);

  gemm_f16_kernel<<<gg, 256, 0, stream>>>(Hd, Wt + 3 * WSZ, nullptr, (float*)d_out, 1);
}

// Round 2
// 234.572 us; speedup vs baseline: 1.3875x; 1.3875x over previous
//
#include <hip/hip_runtime.h>

#define B_ 2
#define N_ 2048
#define D_ 1024
#define H_ 16
#define DH_ 64

typedef _Float16 half8 __attribute__((ext_vector_type(8)));
typedef _Float16 half4 __attribute__((ext_vector_type(4)));
typedef float f32x4 __attribute__((ext_vector_type(4)));

__device__ __forceinline__ void gl2lds16(const _Float16* g, _Float16* l) {
  __builtin_amdgcn_global_load_lds(
      (const __attribute__((address_space(1))) void*)g,
      (__attribute__((address_space(3))) void*)l, 16, 0, 0);
}

// ---------------------------------------------------------------------------
// Convert fp32 inputs (queries/keys/values) to fp16, same layout (B,N,D).
__global__ __launch_bounds__(256) void convert_x_kernel(
    const float* __restrict__ q, const float* __restrict__ k,
    const float* __restrict__ v, _Float16* __restrict__ dst) {
  const float* s = (blockIdx.y == 0) ? q : (blockIdx.y == 1) ? k : v;
  _Float16* d = dst + (size_t)blockIdx.y * ((size_t)B_ * N_ * D_);
  size_t idx = ((size_t)blockIdx.x * 256 + threadIdx.x) * 8;
  float4 a = *(const float4*)(s + idx);
  float4 b = *(const float4*)(s + idx + 4);
  half8 h;
  h[0] = (_Float16)a.x; h[1] = (_Float16)a.y; h[2] = (_Float16)a.z; h[3] = (_Float16)a.w;
  h[4] = (_Float16)b.x; h[5] = (_Float16)b.y; h[6] = (_Float16)b.z; h[7] = (_Float16)b.w;
  *(half8*)(d + idx) = h;
}

// ---------------------------------------------------------------------------
// Convert+transpose the four (D,D) fp32 weights to fp16 W^T (N-major, K-contig).
__global__ __launch_bounds__(256) void convert_w_kernel(
    const float* __restrict__ Wq, const float* __restrict__ Wk,
    const float* __restrict__ Wv, const float* __restrict__ Wo,
    _Float16* __restrict__ WtAll) {
  const float* W = (blockIdx.z == 0) ? Wq : (blockIdx.z == 1) ? Wk
                  : (blockIdx.z == 2) ? Wv : Wo;
  _Float16* Wt = WtAll + (size_t)blockIdx.z * D_ * D_;
  __shared__ float tile[64][65];
  int k0 = blockIdx.y * 64, n0 = blockIdx.x * 64;
  int tr = threadIdx.x >> 4, tc = threadIdx.x & 15;
#pragma unroll
  for (int i = 0; i < 4; ++i) {
    int r = tr + i * 16;
    float4 va = *(const float4*)(W + (size_t)(k0 + r) * D_ + n0 + tc * 4);
    tile[r][tc * 4 + 0] = va.x; tile[r][tc * 4 + 1] = va.y;
    tile[r][tc * 4 + 2] = va.z; tile[r][tc * 4 + 3] = va.w;
  }
  __syncthreads();
#pragma unroll
  for (int i = 0; i < 4; ++i) {
    int r = tr + i * 16;
    half4 hv;
    hv[0] = (_Float16)tile[tc * 4 + 0][r];
    hv[1] = (_Float16)tile[tc * 4 + 1][r];
    hv[2] = (_Float16)tile[tc * 4 + 2][r];
    hv[3] = (_Float16)tile[tc * 4 + 3][r];
    *(half4*)(Wt + (size_t)(n0 + r) * D_ + k0 + tc * 4) = hv;
  }
}

// ---------------------------------------------------------------------------
// fp16 MFMA GEMM: C[128-tile of M=4096, BN-tile of N=1024] = A * Bt^T, K=1024.
// NT = n-tiles (16 cols) per wave; BN = NT*32 (2 waves across n).
// MODE 0: fp16 head-split (B,H,N,DH) output; MODE 1: fp32 row-major output.
// global_load_lds width-16 staging, XOR-swizzled LDS (conflict-free).
#define BK 32

template <int NT, int MODE>
__global__ __launch_bounds__(256) void gemm_f16_kernel(
    const _Float16* __restrict__ Aall, const _Float16* __restrict__ Btall,
    _Float16* __restrict__ ChAll, float* __restrict__ Cf32) {
  constexpr int BN = NT * 32;
  constexpr int K = D_;
  __shared__ __attribute__((aligned(16))) _Float16 As[128 * BK];
  __shared__ __attribute__((aligned(16))) _Float16 Bs[BN * BK];
  const int z = blockIdx.z;
  const _Float16* A  = Aall  + (size_t)z * ((size_t)B_ * N_ * D_);
  const _Float16* Bt = Btall + (size_t)z * ((size_t)D_ * D_);
  _Float16* Chead = ChAll + (size_t)z * ((size_t)B_ * N_ * D_);

  const int tid = threadIdx.x;
  const int m0 = blockIdx.y * 128, n0 = blockIdx.x * BN;
  const int lane = tid & 63, w = tid >> 6;
  const int quad = lane >> 4, l15 = lane & 15;
  const int wm = (w >> 1) * 64, wn = (w & 1) * (BN / 2);
  const int swz = (quad ^ ((l15 >> 1) & 3)) * 8;  // swizzled 16B-chunk offset
  f32x4 acc[4][NT] = {};

  for (int kt = 0; kt < K; kt += BK) {
    if (kt) __syncthreads();
#pragma unroll
    for (int p = 0; p < 2; ++p) {
      int c = p * 256 + tid;
      int row = c >> 2, pg = c & 3;
      int gl = pg ^ ((row >> 1) & 3);
      gl2lds16(A + (size_t)(m0 + row) * K + kt + gl * 8, &As[c * 8]);
    }
#pragma unroll
    for (int p = 0; p < NT / 2; ++p) {
      int c = p * 256 + tid;
      int row = c >> 2, pg = c & 3;
      int gl = pg ^ ((row >> 1) & 3);
      gl2lds16(Bt + (size_t)(n0 + row) * K + kt + gl * 8, &Bs[c * 8]);
    }
    __syncthreads();
    half8 af[4], bf[NT];
#pragma unroll
    for (int mt = 0; mt < 4; ++mt)
      af[mt] = *(const half8*)&As[(wm + mt * 16 + l15) * 32 + swz];
#pragma unroll
    for (int nt = 0; nt < NT; ++nt)
      bf[nt] = *(const half8*)&Bs[(wn + nt * 16 + l15) * 32 + swz];
#pragma unroll
    for (int mt = 0; mt < 4; ++mt)
#pragma unroll
      for (int nt = 0; nt < NT; ++nt)
        acc[mt][nt] = __builtin_amdgcn_mfma_f32_16x16x32_f16(
            af[mt], bf[nt], acc[mt][nt], 0, 0, 0);
  }

#pragma unroll
  for (int mt = 0; mt < 4; ++mt) {
    int mrow = m0 + wm + mt * 16 + quad * 4;
#pragma unroll
    for (int nt = 0; nt < NT; ++nt) {
      int jcol = n0 + wn + nt * 16 + l15;
#pragma unroll
      for (int r = 0; r < 4; ++r) {
        float val = acc[mt][nt][r];
        int m = mrow + r;
        if (MODE == 0) {
          int b = m >> 11, n = m & (N_ - 1);
          int h = jcol >> 6, dh = jcol & (DH_ - 1);
          Chead[((((size_t)(b * H_ + h)) * N_ + n) * DH_) + dh] = (_Float16)val;
        } else {
          Cf32[(size_t)m * D_ + jcol] = val;
        }
      }
    }
  }
}

// ---------------------------------------------------------------------------
// Flash attention, S^T formulation. grid (N/64, B*H), 256 threads (4 waves).
// S^T = K·Q^T so softmax reduces per-lane (2 cross-quad shuffles), and the
// P^T C-layout IS the 16x16x16 MFMA B-fragment layout -> PV with no LDS/shuffle.
// LDS: swizzled unpadded Qs/Ks (conflict-free b128) + swizzled Vt. 24KB/block.
__global__ __launch_bounds__(256, 4) void attn_kernel(
    const _Float16* __restrict__ Qh, const _Float16* __restrict__ Kh,
    const _Float16* __restrict__ Vh, const int* __restrict__ vlen,
    _Float16* __restrict__ Hd) {
  __shared__ __attribute__((aligned(16))) _Float16 Qs[64 * 64];
  __shared__ __attribute__((aligned(16))) _Float16 Ks[64 * 64];
  __shared__ __attribute__((aligned(16))) _Float16 Vt[64 * 64];  // [dh][key] swizzled
  const int bh = blockIdx.y, q0 = blockIdx.x * 64;
  const int b = bh >> 4, h = bh & (H_ - 1);
  const int vl = vlen[bh];
  const int tid = threadIdx.x, lane = tid & 63, w = tid >> 6;
  const int quad = lane >> 4, l15 = lane & 15;
  const _Float16* Qb = Qh + (size_t)bh * N_ * DH_;
  const _Float16* Kb = Kh + (size_t)bh * N_ * DH_;
  const _Float16* Vb = Vh + (size_t)bh * N_ * DH_;

  // stage Q (64x64, swizzled) once
#pragma unroll
  for (int p = 0; p < 2; ++p) {
    int c = p * 256 + tid;
    int row = c >> 3, pg = c & 7, g = pg ^ (row & 7);
    *(half8*)&Qs[c * 8] = *(const half8*)(Qb + (size_t)(q0 + row) * DH_ + g * 8);
  }

  // register prefetch of K/V tile
  half8 kpre[2], vpre[2];
  auto prefetch = [&](int k0) {
#pragma unroll
    for (int p = 0; p < 2; ++p) {
      int c = p * 256 + tid;
      int row = c >> 3, pg = c & 7, g = pg ^ (row & 7);
      kpre[p] = *(const half8*)(Kb + (size_t)(k0 + row) * DH_ + g * 8);
      vpre[p] = *(const half8*)(Vb + (size_t)(k0 + lane) * DH_ + (w + p * 4) * 8);
    }
  };
  prefetch(0);

  __syncthreads();  // Qs visible
  const int sw  = (quad ^ (l15 & 7)) * 8;
  const int sw2 = ((quad + 4) ^ (l15 & 7)) * 8;
  const half8 qb0 = *(const half8*)&Qs[(w * 16 + l15) * 64 + sw];
  const half8 qb1 = *(const half8*)&Qs[(w * 16 + l15) * 64 + sw2];

  float m_i = -1e30f, l_i = 0.f;
  f32x4 Oacc[4] = {};
  const float scale = 0.125f;  // 1/sqrt(64)
  const int KT = (vl + 63) >> 6;

  for (int kt = 0; kt < KT; ++kt) {
    __syncthreads();  // (A) prev-iter LDS reads complete
    // commit prefetched K (vector) and V (transposed, swizzled scalar)
#pragma unroll
    for (int p = 0; p < 2; ++p) {
      int c = p * 256 + tid;
      *(half8*)&Ks[c * 8] = kpre[p];
      int dhg = w + p * 4;
#pragma unroll
      for (int u = 0; u < 8; ++u) {
        int dh = dhg * 8 + u;
        Vt[dh * 64 + (((lane >> 2) ^ (dh & 15)) << 2) + (lane & 3)] = vpre[p][u];
      }
    }
    __syncthreads();  // (B)
    if (kt + 1 < KT) prefetch((kt + 1) * 64);

    // S^T = K·Q^T : C rows = key, cols = q
    f32x4 s[4];
#pragma unroll
    for (int nt = 0; nt < 4; ++nt) {
      int r = nt * 16 + l15;
      half8 ka0 = *(const half8*)&Ks[r * 64 + sw];
      half8 ka1 = *(const half8*)&Ks[r * 64 + sw2];
      f32x4 c = {};
      c = __builtin_amdgcn_mfma_f32_16x16x32_f16(ka0, qb0, c, 0, 0, 0);
      c = __builtin_amdgcn_mfma_f32_16x16x32_f16(ka1, qb1, c, 0, 0, 0);
      s[nt] = c;
    }
    int k0 = kt * 64;
#pragma unroll
    for (int nt = 0; nt < 4; ++nt) {
      int keyb = k0 + nt * 16 + quad * 4;
#pragma unroll
      for (int r = 0; r < 4; ++r)
        s[nt][r] = (keyb + r < vl) ? s[nt][r] * scale : -1e30f;
    }
    // online softmax: per-lane over 16 regs, then 2 cross-quad shuffles
    float mx = s[0][0];
#pragma unroll
    for (int nt = 0; nt < 4; ++nt)
#pragma unroll
      for (int r = 0; r < 4; ++r) mx = fmaxf(mx, s[nt][r]);
    mx = fmaxf(mx, __shfl_xor(mx, 16));
    mx = fmaxf(mx, __shfl_xor(mx, 32));
    float mi = fmaxf(m_i, mx);
    float alpha = __expf(m_i - mi);
    m_i = mi;
    float sum = 0.f;
    half4 pf[4];
#pragma unroll
    for (int nt = 0; nt < 4; ++nt)
#pragma unroll
      for (int r = 0; r < 4; ++r) {
        float p = __expf(s[nt][r] - mi);
        sum += p;
        pf[nt][r] = (_Float16)p;
      }
    sum += __shfl_xor(sum, 16);
    sum += __shfl_xor(sum, 32);
    l_i = alpha * l_i + sum;
#pragma unroll
    for (int dt = 0; dt < 4; ++dt)
#pragma unroll
      for (int r = 0; r < 4; ++r) Oacc[dt][r] *= alpha;
    // O^T += V^T · P^T : P^T regs are already the 16x16x16 B-fragment
#pragma unroll
    for (int dt = 0; dt < 4; ++dt) {
      int dh = dt * 16 + l15;
#pragma unroll
      for (int nt = 0; nt < 4; ++nt) {
        half4 va = *(const half4*)&Vt[dh * 64 + (((nt * 4 + quad) ^ l15) << 2)];
        Oacc[dt] = __builtin_amdgcn_mfma_f32_16x16x16f16(va, pf[nt], Oacc[dt], 0, 0, 0);
      }
    }
  }

  // epilogue: O^T[dh][q] -> Hd[(b,q), h*64+dh], fp16
  float inv_l = 1.0f / l_i;
  int q = q0 + w * 16 + l15;
  _Float16* out = Hd + ((size_t)(b * N_ + q)) * D_ + h * DH_;
#pragma unroll
  for (int dt = 0; dt < 4; ++dt) {
    half4 o;
#pragma unroll
    for (int r = 0; r < 4; ++r) o[r] = (_Float16)(Oacc[dt][r] * inv_l);
    *(half4*)(out + dt * 16 + quad * 4) = o;
  }
}

// ---------------------------------------------------------------------------
extern "C" void kernel_launch(void* const* d_in, const int* in_sizes, int n_in,
                              void* d_out, int out_size, void* d_ws, size_t ws_size,
                              hipStream_t stream) {
  const float* q  = (const float*)d_in[0];
  const float* k  = (const float*)d_in[1];
  const float* v  = (const float*)d_in[2];
  const int*   vl = (const int*)d_in[3];
  const float* Wq = (const float*)d_in[4];
  const float* Wk = (const float*)d_in[5];
  const float* Wv = (const float*)d_in[6];
  const float* Wo = (const float*)d_in[7];

  const size_t XSZ = (size_t)B_ * N_ * D_;  // 4M elements
  const size_t WSZ = (size_t)D_ * D_;       // 1M elements
  _Float16* ws = (_Float16*)d_ws;
  _Float16* Xf = ws;                 // 3*XSZ (fp16 q,k,v inputs)
  _Float16* Wt = Xf + 3 * XSZ;       // 4*WSZ (fp16 W^T x4)
  _Float16* Qh = Wt + 4 * WSZ;       // 3*XSZ (Qh,Kh,Vh contiguous)
  _Float16* Hd = Qh + 3 * XSZ;       // XSZ

  convert_x_kernel<<<dim3(2048, 3), 256, 0, stream>>>(q, k, v, Xf);
  convert_w_kernel<<<dim3(16, 16, 4), 256, 0, stream>>>(Wq, Wk, Wv, Wo, Wt);

  // fused Q/K/V projections: z selects input/weight/output
  gemm_f16_kernel<4, 0><<<dim3(D_ / 128, 32, 3), 256, 0, stream>>>(
      Xf, Wt, Qh, nullptr);

  attn_kernel<<<dim3(N_ / 64, B_ * H_), 256, 0, stream>>>(
      Qh, Qh + XSZ, Qh + 2 * XSZ, vl, Hd);

  // output projection (BN=64 -> 512 blocks)
  gemm_f16_kernel<2, 1><<<dim3(D_ / 64, 32, 1), 256, 0, stream>>>(
      Hd, Wt + 3 * WSZ, nullptr, (float*)d_out);
}